// Round 1
// baseline (168.188 us; speedup 1.0000x reference)
//
#include <hip/hip_runtime.h>
#include <float.h>

// Problem constants (from reference): x is (B=64, C=256, H=64, W=64) fp32,
// top-k (k=8) per batch over flattened C*H*W, output [B, 8, C+3] fp32.
#define BB   64
#define CC   256
#define HH   64
#define WW   64
#define K    8
#define NPB  (CC * HH * WW)      // 1048576 elements per batch
#define NBLK 32                  // partial blocks per batch
#define TPB  256
#define CHUNK (NPB / NBLK)       // 32768 elements per block
#define VECS  (CHUNK / (TPB * 4))// 32 float4 per thread
#define OUTC  (CC + 3)           // 259

// Total order matching lax.top_k: larger value wins; ties -> lower index wins.
__device__ __forceinline__ bool cand_gt(float v1, int i1, float v2, int i2) {
    return (v1 > v2) || (v1 == v2 && i1 < i2);
}

// Insert (nv, ni) into descending sorted (v, ix) of length K.
// Fully unrolled, static indices only (no scratch spill).
__device__ __forceinline__ void insert8(float nv, int ni, float (&v)[K], int (&ix)[K]) {
    if (!cand_gt(nv, ni, v[K - 1], ix[K - 1])) return;
    bool gt[K];
#pragma unroll
    for (int p = 0; p < K; ++p) gt[p] = cand_gt(nv, ni, v[p], ix[p]);
#pragma unroll
    for (int p = K - 1; p > 0; --p) {
        if (gt[p - 1]) { v[p] = v[p - 1]; ix[p] = ix[p - 1]; }
    }
#pragma unroll
    for (int p = 0; p < K; ++p) {
        if (gt[p] && (p == 0 || !gt[p - 1])) { v[p] = nv; ix[p] = ni; }
    }
}

// Merge my sorted-8 list with partner lane's sorted-8 list (shfl_xor d),
// keep top-8, sorted descending. Bitonic: stage0 pairs a[i] vs b[7-i],
// then bitonic-merge distances 4,2,1. All static indices.
__device__ __forceinline__ void merge_shfl(int d, float (&v)[K], int (&ix)[K]) {
    float ov[K]; int oi[K];
#pragma unroll
    for (int p = 0; p < K; ++p) {
        ov[p] = __shfl_xor(v[p], d, 64);
        oi[p] = __shfl_xor(ix[p], d, 64);
    }
    float mv[K]; int mi[K];
#pragma unroll
    for (int p = 0; p < K; ++p) {
        bool a = cand_gt(v[p], ix[p], ov[K - 1 - p], oi[K - 1 - p]);
        mv[p] = a ? v[p] : ov[K - 1 - p];
        mi[p] = a ? ix[p] : oi[K - 1 - p];
    }
#pragma unroll
    for (int dd = 4; dd >= 1; dd >>= 1) {
#pragma unroll
        for (int i = 0; i < K; ++i) {
            if ((i & dd) == 0) {
                int j = i + dd;
                if (cand_gt(mv[j], mi[j], mv[i], mi[i])) {
                    float tv = mv[i]; mv[i] = mv[j]; mv[j] = tv;
                    int   ti = mi[i]; mi[i] = mi[j]; mi[j] = ti;
                }
            }
        }
    }
#pragma unroll
    for (int p = 0; p < K; ++p) { v[p] = mv[p]; ix[p] = mi[p]; }
}

__global__ __launch_bounds__(TPB) void topk_partial(const float* __restrict__ x,
                                                    float* __restrict__ wval,
                                                    int* __restrict__ widx) {
    const int b   = blockIdx.x / NBLK;
    const int blk = blockIdx.x % NBLK;
    const int t   = threadIdx.x;
    const float* xb = x + (size_t)b * NPB + (size_t)blk * CHUNK;
    const int base = blk * CHUNK;  // index-within-batch offset of this chunk

    float v[K]; int ix[K];
#pragma unroll
    for (int p = 0; p < K; ++p) { v[p] = -FLT_MAX; ix[p] = 0x7fffffff; }

#pragma unroll 2
    for (int it = 0; it < VECS; ++it) {
        const int e = (it * TPB + t) * 4;        // coalesced: lane stride 16B
        const float4 f = *reinterpret_cast<const float4*>(xb + e);
        const float vals[4] = {f.x, f.y, f.z, f.w};
#pragma unroll
        for (int j = 0; j < 4; ++j) {
            // cheap guard: most elements lose to current 8th-largest
            if (vals[j] > v[K - 1]) insert8(vals[j], base + e + j, v, ix);
        }
    }

    // Dump all per-thread top-8s to LDS; one wave re-reduces.
    __shared__ float sv[TPB * K];
    __shared__ int   si[TPB * K];
#pragma unroll
    for (int p = 0; p < K; ++p) { sv[p * TPB + t] = v[p]; si[p * TPB + t] = ix[p]; }
    __syncthreads();

    if (t < 64) {
        float mv[K]; int mi[K];
#pragma unroll
        for (int p = 0; p < K; ++p) { mv[p] = -FLT_MAX; mi[p] = 0x7fffffff; }
        for (int j = t; j < TPB * K; j += 64) {
            float nv = sv[j]; int ni = si[j];
            if (cand_gt(nv, ni, mv[K - 1], mi[K - 1])) insert8(nv, ni, mv, mi);
        }
        // 64 -> 1 butterfly; every lane ends with the block's top-8.
        merge_shfl(1,  mv, mi);
        merge_shfl(2,  mv, mi);
        merge_shfl(4,  mv, mi);
        merge_shfl(8,  mv, mi);
        merge_shfl(16, mv, mi);
        merge_shfl(32, mv, mi);
        if (t == 0) {
            const int ob = blockIdx.x * K;
#pragma unroll
            for (int p = 0; p < K; ++p) { wval[ob + p] = mv[p]; widx[ob + p] = mi[p]; }
        }
    }
}

__global__ __launch_bounds__(TPB) void topk_final(const float* __restrict__ wval,
                                                  const int* __restrict__ widx,
                                                  float* __restrict__ out) {
    const int b = blockIdx.x;
    const int t = threadIdx.x;

    __shared__ float sv[NBLK * K];   // 256 candidates
    __shared__ int   si[NBLK * K];
    sv[t] = wval[(size_t)b * NBLK * K + t];
    si[t] = widx[(size_t)b * NBLK * K + t];

    // Zero this batch's whole output block first (harness poisons d_out).
    float* ob = out + (size_t)b * K * OUTC;
    for (int j = t; j < K * OUTC; j += TPB) ob[j] = 0.0f;
    __syncthreads();

    __shared__ float rv[TPB];
    __shared__ int   ri[TPB];
    __shared__ int   rp[TPB];

    for (int r = 0; r < K; ++r) {
        rv[t] = sv[t]; ri[t] = si[t]; rp[t] = t;
        __syncthreads();
#pragma unroll
        for (int s = TPB / 2; s > 0; s >>= 1) {
            if (t < s) {
                if (cand_gt(rv[t + s], ri[t + s], rv[t], ri[t])) {
                    rv[t] = rv[t + s]; ri[t] = ri[t + s]; rp[t] = rp[t + s];
                }
            }
            __syncthreads();
        }
        if (t == 0) {
            const float val = rv[0];
            const int   idx = ri[0];
            sv[rp[0]] = -FLT_MAX;            // remove winner for next round
            si[rp[0]] = 0x7fffffff;
            const int c   = idx >> 12;       // / (H*W) = /4096
            const int rem = idx & 4095;
            const int yy  = rem >> 6;        // / W
            const int xx  = rem & 63;        // % W
            float* row = ob + r * OUTC;
            row[c]      = 1.0f;
            row[CC]     = val;
            row[CC + 1] = (float)xx / 63.0f; // xn, exact fp32 divide
            row[CC + 2] = (float)yy / 63.0f; // yn
        }
        __syncthreads();
    }
}

extern "C" void kernel_launch(void* const* d_in, const int* in_sizes, int n_in,
                              void* d_out, int out_size, void* d_ws, size_t ws_size,
                              hipStream_t stream) {
    const float* x = (const float*)d_in[0];
    float* out = (float*)d_out;
    // workspace: 2048 blocks * 8 vals (64KB) + 2048 * 8 idx (64KB) = 128KB
    float* wval = (float*)d_ws;
    int*   widx = (int*)((char*)d_ws + (size_t)BB * NBLK * K * sizeof(float));

    topk_partial<<<BB * NBLK, TPB, 0, stream>>>(x, wval, widx);
    topk_final<<<BB, TPB, 0, stream>>>(wval, widx, out);
}